// Round 11
// baseline (110.042 us; speedup 1.0000x reference)
//
#include <hip/hip_runtime.h>

typedef __attribute__((ext_vector_type(4))) float          f32x4;
typedef __attribute__((ext_vector_type(2))) float          f32x2;
typedef __attribute__((ext_vector_type(4))) unsigned int   u32x4;
typedef __attribute__((ext_vector_type(4))) unsigned short u16x4;
typedef __attribute__((ext_vector_type(2))) unsigned short u16x2;

typedef const unsigned int __attribute__((address_space(1)))* gas_ptr;
typedef unsigned int __attribute__((address_space(3)))*       las_ptr;

#define PI_F 3.14159265358979f

__device__ __forceinline__ unsigned short f2bf(float f) {
    unsigned int x = __float_as_uint(f);
    unsigned int r = ((x >> 16) & 1u) + 0x7fffu;
    return (unsigned short)((x + r) >> 16);
}
__device__ __forceinline__ float bf2f(unsigned short v) {
    return __uint_as_float((unsigned int)v << 16);
}
__device__ __forceinline__ void mfma16(f32x4& c, u32x4 a, u32x4 b) {
    asm volatile("v_mfma_f32_16x16x32_bf16 %0, %1, %2, %0"
                 : "+v"(c) : "v"(a), "v"(b));
}
__device__ __forceinline__ void gload16(const void* g, void* l) {
    __builtin_amdgcn_global_load_lds((gas_ptr)g, (las_ptr)l, 16, 0, 0);
}

// Pre-swizzled global format (verified r4-r10): 256x256 bf16, row stride 512B;
// within each 64-elem K-quarter of row r, element k stored at k ^ ((r&7)<<3).
#define SWZ(r, cb) (((unsigned)(r) * 128u) + ((unsigned)(cb) ^ ((((unsigned)(r)) & 7u) << 4)))

// prep: hbuild (blocks 0..2047) + xconv (2048..6143) + abc rank-1 terms (6144..6207).
// abc_out[n*768 + j] = a_j = sum_i (-1)^i x[n,i,j]
// abc_out[n*768+256+i] = b_i = sum_j (-1)^j x[n,i,j]
// abc_out[n*768+512]   = c   = sum_ij (-1)^(i+j) x[n,i,j]
__global__ void prep(const float* __restrict__ x, unsigned short* __restrict__ H,
                     unsigned short* __restrict__ Xb, float* __restrict__ out,
                     float* __restrict__ abc_out, int write_c0) {
    int b = blockIdx.x;
    if (b < 2048) {
        const int US[8] = {5, 22, 39, 57, 74, 92, 109, 127};
        int idx = b * 256 + threadIdx.x;
        int u = idx >> 16;
        int i = (idx >> 8) & 255, js = idx & 255;
        int jl = js ^ ((i & 7) << 3);
        int d = (i - jl) & 255;
        int m = 2 * US[u] + 1;
        float h;
        if (d == 0) {
            h = (float)m * (1.0f / 256.0f);
        } else {
            int t = (m * d) & 511;
            float num = sinf((float)t * (PI_F / 256.0f));
            float den = sinf((float)d * (PI_F / 256.0f));
            h = num / (256.0f * den);
        }
        H[idx] = f2bf(h);
    } else if (b < 6144) {
        int idx = (b - 2048) * 256 + threadIdx.x;   // u16x4 units
        f32x4 v = ((const f32x4*)x)[idx];
        u16x4 o = { f2bf(v.x), f2bf(v.y), f2bf(v.z), f2bf(v.w) };
        int n = idx >> 14;
        int t = idx & 16383;
        int i = t >> 6;
        int jlin = (t & 63) * 4;
        int js = jlin ^ ((i & 7) << 3);
        *(u16x4*)(Xb + (size_t)n * 65536 + i * 256 + js) = o;
        if (write_c0) {
            size_t g = (size_t)idx * 4;
            out[(g + 0) * 9] = v.x;
            out[(g + 1) * 9] = v.y;
            out[(g + 2) * 9] = v.z;
            out[(g + 3) * 9] = v.w;
        }
    } else {
        // abc: one block per image
        __shared__ float cw[4];
        int n = b - 6144, t = threadIdx.x;
        int w = t >> 6, lane = t & 63;
        const float* xi = x + (size_t)n * 65536;
        float sa = 0.f;
        for (int i = 0; i < 256; ++i) {            // coalesced column walk
            float v = xi[i * 256 + t];
            sa += (i & 1) ? -v : v;
        }
        float sb = 0.f;
        for (int jb = 0; jb < 64; ++jb) {          // own-row walk (L1/L2 resident)
            f32x4 v4 = *(const f32x4*)(xi + t * 256 + jb * 4);
            sb += (v4.x - v4.y) + (v4.z - v4.w);   // signs +,-,+,- (j=4jb..)
        }
        abc_out[n * 768 + t]       = sa;           // a[j=t]
        abc_out[n * 768 + 256 + t] = sb;           // b[i=t]
        float sc = (t & 1) ? -sb : sb;             // c = sum_i (-1)^i b_i
        for (int off = 32; off; off >>= 1) sc += __shfl_down(sc, off);
        if (lane == 0) cw[w] = sc;
        __syncthreads();
        if (t == 0) abc_out[n * 768 + 512] = cw[0] + cw[1] + cw[2] + cw[3];
    }
}

// stage12: r7's verified body (fastest measured variant), u range 0..6 in full path.
// Block = (n, u, jq), 4 waves, 72 KB dynamic LDS -> 2 blocks/CU.
__global__ void __launch_bounds__(256) stage12(const unsigned short* __restrict__ Xb,
                                               const unsigned short* __restrict__ H,
                                               unsigned short* __restrict__ Zb,
                                               float* __restrict__ fOut,
                                               int mode, int u_fixed) {
    extern __shared__ char smem[];
    char* sStage = smem;            // 32KB: 256 rows x 128B
    char* sHq    = smem + 32768;    //  8KB:  64 rows x 128B (H j-quarter rows)
    char* sT     = smem + 40960;    // 32KB:  64 rows x 512B (T^T, swizzled)

    int n, u, jq;
    if (u_fixed >= 0) {
        n = blockIdx.x >> 2; jq = blockIdx.x & 3; u = u_fixed;
    } else {
        int swz = (blockIdx.x & 7) * 224 + (blockIdx.x >> 3);  // 1792 = 8*224, bijective
        n = swz / 28;
        int rr = swz - n * 28;
        u = rr >> 2; jq = rr & 3;
    }

    const char* Xn = (const char*)(Xb + (size_t)n * 65536);
    const char* Hu = (const char*)(H + (size_t)u * 65536);

    const int tid  = threadIdx.x;
    const int lane = tid & 63;
    const int w    = tid >> 6;        // 0..3
    const int lrow = lane & 15;
    const int lk   = lane >> 4;
    const int srow = lane >> 3, sch = lane & 7;

    f32x4 acc[4][4];
#pragma unroll
    for (int a = 0; a < 4; ++a)
#pragma unroll
        for (int b = 0; b < 4; ++b) acc[a][b] = (f32x4){0.f, 0.f, 0.f, 0.f};

    // ---------------- phase A: sT[jl][i] = T[i, jq*64+jl] ----------------
    for (int kt = 0; kt < 4; ++kt) {
        if (kt) __syncthreads();
#pragma unroll
        for (int q = 0; q < 8; ++q) {      // X rows 0..255 (kt-quarter)
            int r = (w * 8 + q) * 8 + srow;
            gload16(Xn + r * 512 + kt * 128 + sch * 16, sStage + (w * 8 + q) * 1024);
        }
#pragma unroll
        for (int q = 0; q < 2; ++q) {      // H rows jq*64 .. +63
            int r = jq * 64 + (w * 2 + q) * 8 + srow;
            gload16(Hu + r * 512 + kt * 128 + sch * 16, sHq + (w * 2 + q) * 1024);
        }
        __syncthreads();                    // drains vmcnt(0)
#pragma unroll
        for (int kk = 0; kk < 2; ++kk) {
            const int kb = kk * 64 + lk * 16;
            u32x4 af[4], bf[4];
#pragma unroll
            for (int mi = 0; mi < 4; ++mi)
                af[mi] = *(const u32x4*)(sStage + SWZ(w * 64 + mi * 16 + lrow, kb));
#pragma unroll
            for (int ni = 0; ni < 4; ++ni)
                bf[ni] = *(const u32x4*)(sHq + SWZ(ni * 16 + lrow, kb));
#pragma unroll
            for (int mi = 0; mi < 4; ++mi)
#pragma unroll
                for (int ni = 0; ni < 4; ++ni)
                    mfma16(acc[mi][ni], af[mi], bf[ni]);
        }
    }
    asm volatile("s_nop 7\n\ts_nop 7");

    // epilogue A -> sT (bf16, row jl stride 512B, byte 2i ^ ((jl&7)<<4))
#pragma unroll
    for (int mi = 0; mi < 4; ++mi) {
        int i4 = w * 64 + mi * 16 + (lane >> 4) * 4;
#pragma unroll
        for (int ni = 0; ni < 4; ++ni) {
            int jl = ni * 16 + lrow;
            u16x4 o = { f2bf(acc[mi][ni].x), f2bf(acc[mi][ni].y),
                        f2bf(acc[mi][ni].z), f2bf(acc[mi][ni].w) };
            *(u16x4*)(sT + jl * 512 + ((2 * i4) ^ ((jl & 7) << 4))) = o;
        }
    }
    __syncthreads();   // sT visible; all phase-A sStage/sHq reads drained

    // ---------------- phase B: Z[i, jg] = sum_m sT[jl,m] H[i,m] ----------------
#pragma unroll
    for (int a = 0; a < 4; ++a)
#pragma unroll
        for (int b = 0; b < 4; ++b) acc[a][b] = (f32x4){0.f, 0.f, 0.f, 0.f};

    for (int kt = 0; kt < 4; ++kt) {
        if (kt) __syncthreads();
#pragma unroll
        for (int q = 0; q < 8; ++q) {      // H rows 0..255 (kt-quarter)
            int r = (w * 8 + q) * 8 + srow;
            gload16(Hu + r * 512 + kt * 128 + sch * 16, sStage + (w * 8 + q) * 1024);
        }
        __syncthreads();
#pragma unroll
        for (int kk = 0; kk < 2; ++kk) {
            const int kb  = kk * 64 + lk * 16;
            const int kbT = kt * 128 + kb;
            u32x4 af[4], bf[4];
#pragma unroll
            for (int mi = 0; mi < 4; ++mi) {
                int r = mi * 16 + lrow;
                af[mi] = *(const u32x4*)(sT + r * 512 + (kbT ^ ((r & 7) << 4)));
            }
#pragma unroll
            for (int ni = 0; ni < 4; ++ni)
                bf[ni] = *(const u32x4*)(sStage + SWZ(w * 64 + ni * 16 + lrow, kb));
#pragma unroll
            for (int mi = 0; mi < 4; ++mi)
#pragma unroll
                for (int ni = 0; ni < 4; ++ni)
                    mfma16(acc[mi][ni], af[mi], bf[ni]);
        }
    }
    asm volatile("s_nop 7\n\ts_nop 7");

    if (mode == 0) {
        unsigned short* Op = Zb + ((size_t)(u * 64 + n)) * 65536 + jq * 64;
#pragma unroll
        for (int mi = 0; mi < 4; ++mi) {
            int r4 = mi * 16 + (lane >> 4) * 4;          // jl (4 consecutive)
#pragma unroll
            for (int ni = 0; ni < 4; ++ni) {
                int c = w * 64 + ni * 16 + lrow;         // i
                u16x4 o = { f2bf(acc[mi][ni].x), f2bf(acc[mi][ni].y),
                            f2bf(acc[mi][ni].z), f2bf(acc[mi][ni].w) };
                *(u16x4*)(Op + (size_t)c * 256 + r4) = o;
            }
        }
    } else {
#pragma unroll
        for (int mi = 0; mi < 4; ++mi) {
            int r4 = mi * 16 + (lane >> 4) * 4;
#pragma unroll
            for (int ni = 0; ni < 4; ++ni) {
                int c = w * 64 + ni * 16 + lrow;
                float* o = fOut + (((size_t)n * 256 + c) * 256 + jq * 64 + r4) * 9 + 1 + u;
                o[0]  = acc[mi][ni].x;
                o[9]  = acc[mi][ni].y;
                o[18] = acc[mi][ni].z;
                o[27] = acc[mi][ni].w;
            }
        }
    }
}

// pack9: ch0 = x, ch1..7 = Zb[0..6], ch8 = rank-1 formula (u=127 exact).
__global__ void __launch_bounds__(256) pack9(const float* __restrict__ x,
                                             const unsigned short* __restrict__ Zb,
                                             const float* __restrict__ abc_in,
                                             float* __restrict__ out) {
    __shared__ float sl[9216];
    const int t = threadIdx.x;
    const size_t g0 = (size_t)blockIdx.x * 1024;
    const int n = (int)(g0 >> 16);
    const float* ab = abc_in + n * 768;
    const float cc = ab[512];

#pragma unroll
    for (int c = 0; c < 2; ++c) {
        int q = c * 512 + t * 2;
        size_t p = g0 + q;
        int j = (int)(p & 255);          // even
        int i = (int)((p >> 8) & 255);
        f32x2 xv = *(const f32x2*)(x + p);
        sl[q * 9]       = xv.x;
        sl[(q + 1) * 9] = xv.y;
#pragma unroll
        for (int u = 0; u < 7; ++u) {
            u16x2 z = *(const u16x2*)(Zb + (size_t)u * 4194304 + p);
            sl[q * 9 + 1 + u]       = bf2f(z.x);
            sl[(q + 1) * 9 + 1 + u] = bf2f(z.y);
        }
        // channel 8: Z127 = X - (v_i a_j + b_i v_j)/256 + c v_i v_j/65536
        float vi  = (i & 1) ? -1.f : 1.f;
        f32x2 aj  = *(const f32x2*)(ab + j);
        float bi  = ab[256 + i];
        float z8a = xv.x - (vi * aj.x + bi) * (1.0f / 256.0f) + cc * vi * (1.0f / 65536.0f);
        float z8b = xv.y - (vi * aj.y - bi) * (1.0f / 256.0f) - cc * vi * (1.0f / 65536.0f);
        sl[q * 9 + 8]       = z8a;
        sl[(q + 1) * 9 + 8] = z8b;
    }
    __syncthreads();
    float* ob = out + g0 * 9;
#pragma unroll
    for (int r = 0; r < 9; ++r) {
        int d = r * 1024 + t * 4;
        *(f32x4*)(ob + d) = *(const f32x4*)&sl[d];
    }
}

extern "C" void kernel_launch(void* const* d_in, const int* in_sizes, int n_in,
                              void* d_out, int out_size, void* d_ws, size_t ws_size,
                              hipStream_t stream) {
    const float* x = (const float*)d_in[0];
    float* out = (float*)d_out;
    char* ws = (char*)d_ws;

    unsigned short* H    = (unsigned short*)(ws);              // 1 MB
    unsigned short* Xb   = (unsigned short*)(ws + 1048576);    // 8 MB
    unsigned short* Zb   = (unsigned short*)(ws + 9437184);    // 56 MB (7 planes)
    float*          abcb = (float*)(ws + 68157440);            // 192 KB

    const size_t NEED_FULL = 76546048ull;
    const size_t LDS_BYTES = 73728;        // 72 KB dynamic -> 2 blocks/CU

    if (ws_size >= NEED_FULL) {
        prep<<<6208, 256, 0, stream>>>(x, H, Xb, out, abcb, 0);
        stage12<<<1792, 256, LDS_BYTES, stream>>>(Xb, H, Zb, nullptr, 0, -1);
        pack9<<<4096, 256, 0, stream>>>(x, Zb, abcb, out);
    } else {
        // minimal-ws fallback: per-u (all 8), fp32 scatter epilogue, no abc
        prep<<<6144, 256, 0, stream>>>(x, H, Xb, out, nullptr, 1);
        for (int u = 0; u < 8; ++u)
            stage12<<<256, 256, LDS_BYTES, stream>>>(Xb, H, nullptr, out, 1, u);
    }
}

// Round 12
// 93.439 us; speedup vs baseline: 1.1777x; 1.1777x over previous
//
#include <hip/hip_runtime.h>

typedef __attribute__((ext_vector_type(4))) float          f32x4;
typedef __attribute__((ext_vector_type(2))) float          f32x2;
typedef __attribute__((ext_vector_type(4))) unsigned int   u32x4;
typedef __attribute__((ext_vector_type(4))) unsigned short u16x4;
typedef __attribute__((ext_vector_type(2))) unsigned short u16x2;

typedef const unsigned int __attribute__((address_space(1)))* gas_ptr;
typedef unsigned int __attribute__((address_space(3)))*       las_ptr;

#define PI_F 3.14159265358979f

__device__ __forceinline__ unsigned short f2bf(float f) {
    unsigned int x = __float_as_uint(f);
    unsigned int r = ((x >> 16) & 1u) + 0x7fffu;
    return (unsigned short)((x + r) >> 16);
}
__device__ __forceinline__ float bf2f(unsigned short v) {
    return __uint_as_float((unsigned int)v << 16);
}
__device__ __forceinline__ void mfma16(f32x4& c, u32x4 a, u32x4 b) {
    asm volatile("v_mfma_f32_16x16x32_bf16 %0, %1, %2, %0"
                 : "+v"(c) : "v"(a), "v"(b));
}
__device__ __forceinline__ void gload16(const void* g, void* l) {
    __builtin_amdgcn_global_load_lds((gas_ptr)g, (las_ptr)l, 16, 0, 0);
}

// Pre-swizzled global format (verified r4-r11): 256x256 bf16, row stride 512B;
// within each 64-elem K-quarter of row r, element k stored at k ^ ((r&7)<<3).
// Fragment bytes for lane (lrow,lk) at k-chunk (kt,kk):
//   row*512 + kt*128 + ((kk*64 + lk*16) ^ ((lrow&7)<<4))     [r8-verified]

// prep: fused hbuild (blocks 0..2047) + xconv (blocks 2048..6143).  (r7 verbatim)
__global__ void prep(const float* __restrict__ x, unsigned short* __restrict__ H,
                     unsigned short* __restrict__ Xb, float* __restrict__ out,
                     int write_c0) {
    int b = blockIdx.x;
    if (b < 2048) {
        const int US[8] = {5, 22, 39, 57, 74, 92, 109, 127};
        int idx = b * 256 + threadIdx.x;
        int u = idx >> 16;
        int i = (idx >> 8) & 255, js = idx & 255;
        int jl = js ^ ((i & 7) << 3);
        int d = (i - jl) & 255;
        int m = 2 * US[u] + 1;
        float h;
        if (d == 0) {
            h = (float)m * (1.0f / 256.0f);
        } else {
            int t = (m * d) & 511;
            float num = sinf((float)t * (PI_F / 256.0f));
            float den = sinf((float)d * (PI_F / 256.0f));
            h = num / (256.0f * den);
        }
        H[idx] = f2bf(h);
    } else {
        int idx = (b - 2048) * 256 + threadIdx.x;   // u16x4 units
        f32x4 v = ((const f32x4*)x)[idx];
        u16x4 o = { f2bf(v.x), f2bf(v.y), f2bf(v.z), f2bf(v.w) };
        int n = idx >> 14;
        int t = idx & 16383;
        int i = t >> 6;
        int jlin = (t & 63) * 4;
        int js = jlin ^ ((i & 7) << 3);
        *(u16x4*)(Xb + (size_t)n * 65536 + i * 256 + js) = o;
        if (write_c0) {
            size_t g = (size_t)idx * 4;
            out[(g + 0) * 9] = v.x;
            out[(g + 1) * 9] = v.y;
            out[(g + 2) * 9] = v.z;
            out[(g + 3) * 9] = v.w;
        }
    }
}

// stage12 v12: reg-resident wave-private operands + once-staged shared operands.
//  phase A: af = own X rows, global->VGPR double-buffered; bf = jq H-slice from
//           sHq (staged ONCE, full K, linear copy of global layout).
//  phase B: af = sT (LDS, read-only); bf = own H rows, global->VGPR dbuf.
//  Barriers: 1 after sHq stage, 1 after sT write. No other sync.
#define LOAD_A(dst, KT)                                                        \
    _Pragma("unroll") for (int kk = 0; kk < 2; ++kk)                           \
    _Pragma("unroll") for (int mi = 0; mi < 4; ++mi)                           \
        dst[kk * 4 + mi] = *(const u32x4*)(Arow[mi] + (KT) * 128 + offA[kk]);

#define COMPUTE_A(BUF, KT)                                                     \
    _Pragma("unroll") for (int kk = 0; kk < 2; ++kk) {                         \
        u32x4 bf[4];                                                           \
        _Pragma("unroll") for (int ni = 0; ni < 4; ++ni)                       \
            bf[ni] = *(const u32x4*)(sHq + (ni * 16 + lrow) * 512 +            \
                                     (KT) * 128 + offA[kk]);                   \
        _Pragma("unroll") for (int mi = 0; mi < 4; ++mi)                       \
        _Pragma("unroll") for (int ni = 0; ni < 4; ++ni)                       \
            mfma16(acc[mi][ni], BUF[kk * 4 + mi], bf[ni]);                     \
    }

#define LOAD_B(dst, KT)                                                        \
    _Pragma("unroll") for (int kk = 0; kk < 2; ++kk)                           \
    _Pragma("unroll") for (int ni = 0; ni < 4; ++ni)                           \
        dst[kk * 4 + ni] = *(const u32x4*)(Brow[ni] + (KT) * 128 + offA[kk]);

#define COMPUTE_B(BUF, KT)                                                     \
    _Pragma("unroll") for (int kk = 0; kk < 2; ++kk) {                         \
        u32x4 af[4];                                                           \
        _Pragma("unroll") for (int mi = 0; mi < 4; ++mi)                       \
            af[mi] = *(const u32x4*)(sT + (mi * 16 + lrow) * 512 +             \
                                     (KT) * 128 + offA[kk]);                   \
        _Pragma("unroll") for (int mi = 0; mi < 4; ++mi)                       \
        _Pragma("unroll") for (int ni = 0; ni < 4; ++ni)                       \
            mfma16(acc[mi][ni], af[mi], BUF[kk * 4 + ni]);                     \
    }

__global__ void __launch_bounds__(256, 2) stage12(const unsigned short* __restrict__ Xb,
                                                  const unsigned short* __restrict__ H,
                                                  unsigned short* __restrict__ Zb,
                                                  float* __restrict__ fOut,
                                                  int mode, int u_fixed) {
    __shared__ char sHq[32768];   // 64 H rows (jq*64..+63), full K, global layout
    __shared__ char sT[32768];    // 64 rows (jl) x 512B (T^T, swizzled)

    int n, u, jq;
    if (u_fixed >= 0) {
        n = blockIdx.x >> 2; jq = blockIdx.x & 3; u = u_fixed;
    } else {
        int swz = (blockIdx.x & 7) * 256 + (blockIdx.x >> 3);  // XCD-chunked, bijective
        n = swz >> 5; u = (swz >> 2) & 7; jq = swz & 3;
    }

    const char* Xn = (const char*)(Xb + (size_t)n * 65536);
    const char* Hu = (const char*)(H + (size_t)u * 65536);

    const int tid  = threadIdx.x;
    const int lane = tid & 63;
    const int w    = tid >> 6;        // 0..3
    const int lrow = lane & 15;
    const int lk   = lane >> 4;
    const int lmask = (lrow & 7) << 4;
    const int offA[2] = { (lk * 16) ^ lmask, (64 + lk * 16) ^ lmask };

    // ---- stage sHq once: linear copy of Hu rows jq*64..+63 (32KB) ----
#pragma unroll
    for (int q = 0; q < 8; ++q)
        gload16(Hu + jq * 32768 + (w * 8 + q) * 1024 + lane * 16,
                sHq + (w * 8 + q) * 1024);

    // own X-row fragment pointers; first two kt buffers issued pre-barrier
    const char* Arow[4];
#pragma unroll
    for (int mi = 0; mi < 4; ++mi)
        Arow[mi] = Xn + (w * 64 + mi * 16 + lrow) * 512;

    u32x4 aC[8], aN[8];
    LOAD_A(aC, 0)
    LOAD_A(aN, 1)

    __syncthreads();   // sHq ready (drains vmcnt; aC/aN land too)

    f32x4 acc[4][4];
#pragma unroll
    for (int a = 0; a < 4; ++a)
#pragma unroll
        for (int b = 0; b < 4; ++b) acc[a][b] = (f32x4){0.f, 0.f, 0.f, 0.f};

    // ---------------- phase A: sT[jl][i] = T[i, jq*64+jl] ----------------
    COMPUTE_A(aC, 0)
    LOAD_A(aC, 2)
    COMPUTE_A(aN, 1)
    LOAD_A(aN, 3)
    COMPUTE_A(aC, 2)
    COMPUTE_A(aN, 3)
    asm volatile("s_nop 7\n\ts_nop 7");

    // epilogue A -> sT (bf16, row jl stride 512B, byte 2i ^ ((jl&7)<<4))
#pragma unroll
    for (int mi = 0; mi < 4; ++mi) {
        int i4 = w * 64 + mi * 16 + (lane >> 4) * 4;
#pragma unroll
        for (int ni = 0; ni < 4; ++ni) {
            int jl = ni * 16 + lrow;
            u16x4 o = { f2bf(acc[mi][ni].x), f2bf(acc[mi][ni].y),
                        f2bf(acc[mi][ni].z), f2bf(acc[mi][ni].w) };
            *(u16x4*)(sT + jl * 512 + ((2 * i4) ^ ((jl & 7) << 4))) = o;
        }
    }
    __syncthreads();   // sT visible to all waves

    // ---------------- phase B: Z[i, jg] = sum_m sT[jl,m] H[i,m] ----------------
#pragma unroll
    for (int a = 0; a < 4; ++a)
#pragma unroll
        for (int b = 0; b < 4; ++b) acc[a][b] = (f32x4){0.f, 0.f, 0.f, 0.f};

    const char* Brow[4];
#pragma unroll
    for (int ni = 0; ni < 4; ++ni)
        Brow[ni] = Hu + (w * 64 + ni * 16 + lrow) * 512;

    LOAD_B(aC, 0)
    LOAD_B(aN, 1)
    COMPUTE_B(aC, 0)
    LOAD_B(aC, 2)
    COMPUTE_B(aN, 1)
    LOAD_B(aN, 3)
    COMPUTE_B(aC, 2)
    COMPUTE_B(aN, 3)
    asm volatile("s_nop 7\n\ts_nop 7");

    if (mode == 0) {
        unsigned short* Op = Zb + ((size_t)(u * 64 + n)) * 65536 + jq * 64;
#pragma unroll
        for (int mi = 0; mi < 4; ++mi) {
            int r4 = mi * 16 + (lane >> 4) * 4;          // jl (4 consecutive)
#pragma unroll
            for (int ni = 0; ni < 4; ++ni) {
                int c = w * 64 + ni * 16 + lrow;         // i
                u16x4 o = { f2bf(acc[mi][ni].x), f2bf(acc[mi][ni].y),
                            f2bf(acc[mi][ni].z), f2bf(acc[mi][ni].w) };
                *(u16x4*)(Op + (size_t)c * 256 + r4) = o;
            }
        }
    } else {
#pragma unroll
        for (int mi = 0; mi < 4; ++mi) {
            int r4 = mi * 16 + (lane >> 4) * 4;
#pragma unroll
            for (int ni = 0; ni < 4; ++ni) {
                int c = w * 64 + ni * 16 + lrow;
                float* o = fOut + (((size_t)n * 256 + c) * 256 + jq * 64 + r4) * 9 + 1 + u;
                o[0]  = acc[mi][ni].x;
                o[9]  = acc[mi][ni].y;
                o[18] = acc[mi][ni].z;
                o[27] = acc[mi][ni].w;
            }
        }
    }
}

// pack9 (r7 verbatim): out[p*9+0]=x[p]; out[p*9+1+u]=Zb[u][p]; contiguous stores.
__global__ void __launch_bounds__(256) pack9(const float* __restrict__ x,
                                             const unsigned short* __restrict__ Zb,
                                             float* __restrict__ out) {
    __shared__ float sl[9216];
    const int t = threadIdx.x;
    const size_t g0 = (size_t)blockIdx.x * 1024;

#pragma unroll
    for (int c = 0; c < 2; ++c) {
        int q = c * 512 + t * 2;
        size_t p = g0 + q;
        f32x2 xv = *(const f32x2*)(x + p);
        sl[q * 9]       = xv.x;
        sl[(q + 1) * 9] = xv.y;
#pragma unroll
        for (int u = 0; u < 8; ++u) {
            u16x2 z = *(const u16x2*)(Zb + (size_t)u * 4194304 + p);
            sl[q * 9 + 1 + u]       = bf2f(z.x);
            sl[(q + 1) * 9 + 1 + u] = bf2f(z.y);
        }
    }
    __syncthreads();
    float* ob = out + g0 * 9;
#pragma unroll
    for (int r = 0; r < 9; ++r) {
        int d = r * 1024 + t * 4;
        *(f32x4*)(ob + d) = *(const f32x4*)&sl[d];
    }
}

extern "C" void kernel_launch(void* const* d_in, const int* in_sizes, int n_in,
                              void* d_out, int out_size, void* d_ws, size_t ws_size,
                              hipStream_t stream) {
    const float* x = (const float*)d_in[0];
    float* out = (float*)d_out;
    char* ws = (char*)d_ws;

    unsigned short* H  = (unsigned short*)(ws);                // 1 MB
    unsigned short* Xb = (unsigned short*)(ws + 1048576);      // 8 MB
    unsigned short* Zb = (unsigned short*)(ws + 9437184);      // 64 MB

    const size_t NEED_FULL = 76546048ull;   // H + Xb + Zb

    if (ws_size >= NEED_FULL) {
        prep<<<6144, 256, 0, stream>>>(x, H, Xb, out, 0);
        stage12<<<2048, 256, 0, stream>>>(Xb, H, Zb, nullptr, 0, -1);
        pack9<<<4096, 256, 0, stream>>>(x, Zb, out);
    } else {
        // minimal-ws fallback (9 MB): per-u, fp32 scatter epilogue
        prep<<<6144, 256, 0, stream>>>(x, H, Xb, out, 1);
        for (int u = 0; u < 8; ++u)
            stage12<<<256, 256, 0, stream>>>(Xb, H, nullptr, out, 1, u);
    }
}